// Round 11
// baseline (308.924 us; speedup 1.0000x reference)
//
#include <hip/hip_runtime.h>

// RGCN: N=50000, E=1.6M, R=8, 128 -> 64 -> 64.
// R22 = R21 (242.5us, absmax 0.0625) with layer-2 COMPLETED:
//   - agg2_sums + gemm_final fused into agg2_gemm: block owns 64 dsts;
//     phase 1: each wave aggregates its 16 dsts' per-(d,r) means (lane=(r,l8),
//     one 4-gather round per dst since mean seg len = 4) + h[d] root copy
//     straight into a 64x[576+8] LDS tile; barrier; phase 2: K=576 MFMA,
//     A-fragments from own LDS rows, B-fragments from the L2-hot 73KB
//     W2stack in global (no B staging).
//   - Deletes the 57.6MB sums write + 57.6MB read and one dispatch boundary
//     (R21 post-mortem: the restructure's byte savings were eaten by exactly
//     this round-trip; visible-dispatch sum ~160us vs 242 total => boundaries
//     matter).
//   - Layer 1 (prep / fused append||gemm1 / finalize / agg1) = R14 verbatim.

constexpr int NN  = 50000;
constexpr int NE  = 1600000;
constexpr int NR  = 8;
constexpr int FIN = 128;
constexpr int FH  = 64;

constexpr int BSH = 7;                       // 128 dst nodes per bucket
constexpr int BN  = 1 << BSH;
constexpr int NB  = (NN + BN - 1) >> BSH;    // 391
constexpr int CAP = 6144;                    // bucket capacity (load ~4092±64)
constexpr int CH  = 4096;                    // edges per append block
constexpr int NAPP = (NE + CH - 1) / CH;     // 391 append blocks
constexpr unsigned XWMAX = (unsigned)(NN - 1) * (NR * 64) + (NR - 1) * 64;
constexpr int K2  = 576;                     // 8 rel * 64 + 64 root
constexpr int K2P = 584;                     // LDS row pitch (shorts)

typedef __attribute__((ext_vector_type(8))) short bf16x8;
typedef __attribute__((ext_vector_type(4))) float f32x4;

__device__ __forceinline__ unsigned short f2bf(float f) {
  unsigned u = __float_as_uint(f);
  u = (u + 0x7fff + ((u >> 16) & 1)) >> 16;   // RNE
  return (unsigned short)u;
}
__device__ __forceinline__ float bf2f(unsigned short b) {
  return __uint_as_float(((unsigned)b) << 16);
}
__device__ __forceinline__ bool edge_ok(unsigned s, unsigned d, unsigned r) {
  return s < NN && d < NN && r < NR;
}

// ---------------- CSR build: append (device body, LDS via pointer) ----------
// LDS: stage[CH] (32768B) | h[NB] | gbase[NB] | sbase[NB] | scur[NB] | wtot[4]
__device__ void append_body(char* smem, int bx,
                            const int* __restrict__ src,
                            const int* __restrict__ dst,
                            const int* __restrict__ et,
                            int* __restrict__ bcur,
                            unsigned* __restrict__ brecs) {
  uint2* stage = (uint2*)smem;
  int* h     = (int*)(smem + (size_t)CH * 8);
  int* gbase = h + NB;
  int* sbase = gbase + NB;
  int* scur  = sbase + NB;
  int* wtot  = scur + NB;

  const int t  = threadIdx.x;
  const int c0 = bx * CH;
  const int m  = min(CH, NE - c0);

  for (int i = t; i < NB; i += 256) h[i] = 0;
  __syncthreads();

  for (int i = t; i < m; i += 256) {
    const unsigned s = (unsigned)src[c0 + i];
    const unsigned d = (unsigned)dst[c0 + i];
    const unsigned r = (unsigned)et[c0 + i];
    if (edge_ok(s, d, r)) atomicAdd(&h[d >> BSH], 1);
  }
  __syncthreads();

  const int v0 = (2 * t < NB) ? h[2 * t] : 0;
  const int v1 = (2 * t + 1 < NB) ? h[2 * t + 1] : 0;
  if (2 * t < NB     && v0) gbase[2 * t]     = atomicAdd(&bcur[2 * t], v0);
  if (2 * t + 1 < NB && v1) gbase[2 * t + 1] = atomicAdd(&bcur[2 * t + 1], v1);
  const int s = v0 + v1;
  int incl = s;
#pragma unroll
  for (int o = 1; o < 64; o <<= 1) {
    int u = __shfl_up(incl, o, 64);
    if ((t & 63) >= o) incl += u;
  }
  if ((t & 63) == 63) wtot[t >> 6] = incl;
  __syncthreads();
  int wo = 0;
  for (int w = 0; w < (t >> 6); ++w) wo += wtot[w];
  const int e = wo + incl - s;
  if (2 * t < NB)     { sbase[2 * t] = e;          scur[2 * t] = e; }
  if (2 * t + 1 < NB) { sbase[2 * t + 1] = e + v0; scur[2 * t + 1] = e + v0; }
  __syncthreads();

  for (int i = t; i < m; i += 256) {
    const unsigned sv = (unsigned)src[c0 + i];
    const unsigned d  = (unsigned)dst[c0 + i];
    const unsigned r  = (unsigned)et[c0 + i];
    if (edge_ok(sv, d, r)) {
      const int p = atomicAdd(&scur[d >> BSH], 1);
      if (p < CH) stage[p] = make_uint2((sv << 10) | (((unsigned)d & (BN - 1)) << 3) | r, d);
    }
  }
  __syncthreads();

  const int M = min(sbase[NB - 1] + h[NB - 1], CH);
  for (int j = t; j < M; j += 256) {
    const uint2 rec = stage[j];
    const int b = (int)(rec.y >> BSH);
    const int idx = min(gbase[b] + (j - sbase[b]), NB * CAP - 1);
    brecs[idx] = rec.x;
  }
}

// ---------------- CSR build: finalize ----------------
// Records: cnt<<25 | sv<<9 | r<<6 (weight 1/cnt via v_rcp in agg1).
// segs[d*8+r] = (absolute segment start << 8) | min(cnt,255) for layer 2.
__global__ void __launch_bounds__(256) bucket_finalize(
    const int* __restrict__ bcur, const unsigned* __restrict__ brecs,
    int* __restrict__ row_start, int* __restrict__ deg,
    unsigned* __restrict__ recs, unsigned* __restrict__ segs) {
  const int b    = blockIdx.x;
  const int base = b * CAP;
  const int m    = min(bcur[b] - base, CAP);
  const int d0   = b << BSH;
  __shared__ int cnt[BN * NR];
  __shared__ int curs[BN * NR];
  __shared__ int wtot[4];
  const int t = threadIdx.x;

  for (int i = t; i < BN * NR; i += 256) cnt[i] = 0;
  __syncthreads();
  for (int i = t; i < m; i += 256) {
    const unsigned rec = brecs[base + i];
    const int dl = (int)((rec >> 3) & (BN - 1));
    const int r  = (int)(rec & 7);
    atomicAdd(&cnt[dl * NR + r], 1);
  }
  __syncthreads();

  const int c0 = cnt[t * 4], c1 = cnt[t * 4 + 1], c2 = cnt[t * 4 + 2], c3 = cnt[t * 4 + 3];
  const int s = c0 + c1 + c2 + c3;
  int incl = s;
#pragma unroll
  for (int o = 1; o < 64; o <<= 1) {
    int u = __shfl_up(incl, o, 64);
    if ((t & 63) >= o) incl += u;
  }
  if ((t & 63) == 63) wtot[t >> 6] = incl;
  __syncthreads();
  int wo = 0;
  for (int w = 0; w < (t >> 6); ++w) wo += wtot[w];
  const int e = wo + incl - s;
  curs[t * 4]     = e;
  curs[t * 4 + 1] = e + c0;
  curs[t * 4 + 2] = e + c0 + c1;
  curs[t * 4 + 3] = e + c0 + c1 + c2;
  __syncthreads();

  if (t < BN) {
    const int d = d0 + t;
    if (d < NN) {
      const int start = curs[t * NR];
      const int end   = (t == BN - 1) ? m : curs[(t + 1) * NR];
      row_start[d] = base + start;
      deg[d]       = end - start;
#pragma unroll
      for (int r = 0; r < NR; ++r) {
        const unsigned st = (unsigned)(base + curs[t * NR + r]);
        const unsigned cn = (unsigned)min(cnt[t * NR + r], 255);
        segs[(size_t)d * NR + r] = (st << 8) | cn;
      }
    }
  }
  __syncthreads();

  for (int i = t; i < m; i += 256) {
    const unsigned rec = brecs[base + i];
    const int dl = (int)((rec >> 3) & (BN - 1));
    const int r  = (int)(rec & 7);
    const unsigned sv = rec >> 10;
    const int p  = atomicAdd(&curs[dl * NR + r], 1);
    const unsigned cn = (unsigned)min(cnt[dl * NR + r], 127);
    recs[base + min(p, CAP - 1)] = (cn << 25) | (sv << 9) | ((unsigned)r << 6);
  }
}

// ---------------- prep: bcur init + weights -> bf16 transposed ----------------
// Wt1: [g][n][k] for g<NR rel + g==NR root (K=FIN), as R14.
// Wt2b: STACKED [n][576]: k = r*64+kk (r<8, W2_r) then 512+kk (W2_root).
__global__ void prep(const float* __restrict__ W1r, const float* __restrict__ W1o,
                     const float* __restrict__ W2r, const float* __restrict__ W2o,
                     unsigned short* __restrict__ Wt1,
                     unsigned short* __restrict__ Wt2b,
                     int* __restrict__ bcur) {
  const int i  = blockIdx.x * blockDim.x + threadIdx.x;
  if (i < NB) bcur[i] = i * CAP;
  const int n1 = (NR + 1) * 64 * FIN;
  const int n2 = 64 * K2;
  if (i < n1) {
    const int g = i / (64 * FIN), rem = i % (64 * FIN);
    const int n = rem / FIN, k = rem % FIN;
    const float* W = (g < NR) ? (W1r + (size_t)g * FIN * 64) : W1o;
    Wt1[i] = f2bf(W[k * 64 + n]);
  } else if (i < n1 + n2) {
    const int j = i - n1;
    const int n = j / K2, c = j % K2;
    float v;
    if (c < 512) {
      const int r = c >> 6, kk = c & 63;
      v = W2r[((size_t)r * 64 + kk) * 64 + n];
    } else {
      const int kk = c - 512;
      v = W2o[(size_t)kk * 64 + n];
    }
    Wt2b[j] = f2bf(v);
  }
}

// ---------------- MFMA GEMM body (R14 verbatim): A in regs, B-dbuf LDS ------
template <int K, bool A_FP32>
__device__ void gemm_body(char* smem, int bx,
                          const void* __restrict__ Av,
                          const unsigned short* __restrict__ Wt,
                          const float* __restrict__ bias,
                          unsigned short* __restrict__ xw,
                          float* __restrict__ root_out) {
  constexpr int KP  = K + 8;
  constexpr int NCH = 64 * (K / 8) / 256;
  constexpr int NKC = K / 32;
  unsigned short* Bs0 = (unsigned short*)smem;   // dbuf halves: 2 x 64*KP
  const int n0  = bx * 64;
  const int tid = threadIdx.x;
  const int wave = tid >> 6, lane = tid & 63;
  const int i16 = lane & 15, quad = lane >> 4;
  const int r0 = wave * 16 + i16;
  const int arow = n0 + r0;

  bf16x8 afrag[NKC];
  if constexpr (A_FP32) {
    const float* A = (const float*)Av;
#pragma unroll
    for (int kc = 0; kc < NKC; ++kc) {
      bf16x8 v = {};
      if (arow < NN) {
        const float* p = A + (size_t)arow * K + kc * 32 + quad * 8;
        const float4 f0 = *(const float4*)p;
        const float4 f1 = *(const float4*)(p + 4);
        v[0] = f2bf(f0.x); v[1] = f2bf(f0.y); v[2] = f2bf(f0.z); v[3] = f2bf(f0.w);
        v[4] = f2bf(f1.x); v[5] = f2bf(f1.y); v[6] = f2bf(f1.z); v[7] = f2bf(f1.w);
      }
      afrag[kc] = v;
    }
  } else {
    const unsigned short* A = (const unsigned short*)Av;
#pragma unroll
    for (int kc = 0; kc < NKC; ++kc) {
      bf16x8 v = {};
      if (arow < NN) v = *(const bf16x8*)(A + (size_t)arow * K + kc * 32 + quad * 8);
      afrag[kc] = v;
    }
  }

  for (int c = 0; c < NCH; ++c) {
    const int idx = tid + c * 256;
    const int row = idx / (K / 8), kp = (idx % (K / 8)) * 8;
    *(bf16x8*)(Bs0 + row * KP + kp) = *(const bf16x8*)(Wt + idx * 8);
  }
  __syncthreads();

  for (int g = 0; g <= NR; ++g) {
    const int buf = g & 1;
    unsigned short* Bc = Bs0 + buf * 64 * KP;
    unsigned short* Bn = Bs0 + (buf ^ 1) * 64 * KP;
    bf16x8 breg[NCH];
    if (g < NR) {
      const unsigned short* Wn = Wt + (size_t)(g + 1) * 64 * K;
#pragma unroll
      for (int c = 0; c < NCH; ++c) breg[c] = *(const bf16x8*)(Wn + (tid + c * 256) * 8);
    }

    f32x4 acc[4] = {};
#pragma unroll
    for (int kc = 0; kc < NKC; ++kc) {
      const int k0 = kc * 32 + quad * 8;
      const bf16x8 a0 = afrag[kc];
      const bf16x8 b0 = *(const bf16x8*)(Bc + (i16)      * KP + k0);
      const bf16x8 b1 = *(const bf16x8*)(Bc + (i16 + 16) * KP + k0);
      const bf16x8 b2 = *(const bf16x8*)(Bc + (i16 + 32) * KP + k0);
      const bf16x8 b3 = *(const bf16x8*)(Bc + (i16 + 48) * KP + k0);
      acc[0] = __builtin_amdgcn_mfma_f32_16x16x32_bf16(a0, b0, acc[0], 0, 0, 0);
      acc[1] = __builtin_amdgcn_mfma_f32_16x16x32_bf16(a0, b1, acc[1], 0, 0, 0);
      acc[2] = __builtin_amdgcn_mfma_f32_16x16x32_bf16(a0, b2, acc[2], 0, 0, 0);
      acc[3] = __builtin_amdgcn_mfma_f32_16x16x32_bf16(a0, b3, acc[3], 0, 0, 0);
    }

    if (g < NR) {
#pragma unroll
      for (int c = 0; c < NCH; ++c) {
        const int idx = tid + c * 256;
        const int row = idx / (K / 8), kp = (idx % (K / 8)) * 8;
        *(bf16x8*)(Bn + row * KP + kp) = breg[c];
      }
#pragma unroll
      for (int reg = 0; reg < 4; ++reg) {
        const int n = n0 + wave * 16 + quad * 4 + reg;
        if (n >= NN) continue;
        unsigned short* p = xw + (size_t)n * (NR * 64) + g * 64 + i16;
#pragma unroll
        for (int ct = 0; ct < 4; ++ct) p[ct * 16] = f2bf(acc[ct][reg]);
      }
    } else {
      float bv[4];
#pragma unroll
      for (int ct = 0; ct < 4; ++ct) bv[ct] = bias[ct * 16 + i16];
#pragma unroll
      for (int reg = 0; reg < 4; ++reg) {
        const int n = n0 + wave * 16 + quad * 4 + reg;
        if (n >= NN) continue;
        float* p = root_out + (size_t)n * 64 + i16;
#pragma unroll
        for (int ct = 0; ct < 4; ++ct) p[ct * 16] = acc[ct][reg] + bv[ct];
      }
    }
    __syncthreads();
  }
}

// ---------------- fused dispatch: append interleaved with gemm1 -------------
__global__ void __launch_bounds__(256) fused_append_gemm1(
    const int* __restrict__ src, const int* __restrict__ dst,
    const int* __restrict__ et, int* __restrict__ bcur,
    unsigned* __restrict__ brecs,
    const float* __restrict__ A, const unsigned short* __restrict__ Wt,
    const float* __restrict__ bias, unsigned short* __restrict__ xw,
    float* __restrict__ root_out) {
  extern __shared__ char smem[];
  const int bx = (int)blockIdx.x;
  if (bx % 3 == 2 && bx / 3 < NAPP)
    append_body(smem, bx / 3, src, dst, et, bcur, brecs);
  else
    gemm_body<FIN, true>(smem, bx - (bx + 1) / 3, A, Wt, bias, xw, root_out);
}

// ---------------- layer-1 aggregation (R14 verbatim): one wave/dst ----------
__global__ void __launch_bounds__(256) agg1(
    const int* __restrict__ row_start, const int* __restrict__ deg,
    const unsigned* __restrict__ recs, const unsigned short* __restrict__ xw,
    const float* __restrict__ root, unsigned short* __restrict__ out_b16) {
  const int gid  = blockIdx.x * blockDim.x + threadIdx.x;
  const int lane = gid & 63;
  const int d    = gid >> 6;
  if (d >= NN) return;
  const int e  = lane >> 3;
  const int l8 = lane & 7;
  const int base = row_start[d];
  const int n    = deg[d];
  const unsigned* po = recs + base;
  const unsigned short* xp = xw + l8 * 8;
  float a[8] = {};

  int i0 = 0;
  for (; i0 + 32 < n; i0 += 64) {
    unsigned rr[8];
#pragma unroll
    for (int sl = 0; sl < 8; ++sl) {
      const int i = i0 + e + 8 * sl;
      rr[sl] = (i < n) ? po[i] : 0u;
    }
    bf16x8 vv[8];
#pragma unroll
    for (int sl = 0; sl < 8; ++sl) {
      const unsigned u = min(rr[sl] & 0x01FFFFFFu, XWMAX);
      vv[sl] = *(const bf16x8*)(xp + u);
    }
#pragma unroll
    for (int sl = 0; sl < 8; ++sl) {
      float w = __builtin_amdgcn_rcpf((float)(rr[sl] >> 25));
      if (i0 + e + 8 * sl >= n) w = 0.f;
#pragma unroll
      for (int q = 0; q < 8; ++q) a[q] += bf2f((unsigned short)vv[sl][q]) * w;
    }
  }
  if (i0 < n) {
    unsigned rr[4];
#pragma unroll
    for (int sl = 0; sl < 4; ++sl) {
      const int i = i0 + e + 8 * sl;
      rr[sl] = (i < n) ? po[i] : 0u;
    }
    bf16x8 vv[4];
#pragma unroll
    for (int sl = 0; sl < 4; ++sl) {
      const unsigned u = min(rr[sl] & 0x01FFFFFFu, XWMAX);
      vv[sl] = *(const bf16x8*)(xp + u);
    }
#pragma unroll
    for (int sl = 0; sl < 4; ++sl) {
      float w = __builtin_amdgcn_rcpf((float)(rr[sl] >> 25));
      if (i0 + e + 8 * sl >= n) w = 0.f;
#pragma unroll
      for (int q = 0; q < 8; ++q) a[q] += bf2f((unsigned short)vv[sl][q]) * w;
    }
  }

#pragma unroll
  for (int q = 0; q < 8; ++q) {
    a[q] += __shfl_xor(a[q], 8, 64);
    a[q] += __shfl_xor(a[q], 16, 64);
    a[q] += __shfl_xor(a[q], 32, 64);
  }

  if (e == 0) {
    const float4 r0 = *(const float4*)(root + (size_t)d * 64 + l8 * 8);
    const float4 r1 = *(const float4*)(root + (size_t)d * 64 + l8 * 8 + 4);
    const float o[8] = {r0.x + a[0], r0.y + a[1], r0.z + a[2], r0.w + a[3],
                        r1.x + a[4], r1.y + a[5], r1.z + a[6], r1.w + a[7]};
    bf16x8 ov;
#pragma unroll
    for (int q = 0; q < 8; ++q) ov[q] = (short)f2bf(fmaxf(o[q], 0.f));
    *(bf16x8*)(out_b16 + (size_t)d * 64 + l8 * 8) = ov;
  }
}

// ---------------- layer-2 fused: per-(d,r) means -> LDS -> K=576 MFMA -------
// Block owns nodes [n0, n0+64). Phase 1: wave w aggregates dsts
// n0+w*16+j (j=0..15); lane=(r,l8): each 8-lane group walks its rel segment
// (mean len 4 -> one 4-gather round), gather source hb (6.4MB, cache-hot);
// writes mean row + h[d] root slot into Ss[64][K2P]. Phase 2: wave w's MFMA
// reads A from its OWN rows (no cross-wave dependency); B-fragments straight
// from global W2stack (73KB, L2-hot). out = Ss @ W2stack + b2.
__global__ void __launch_bounds__(256) agg2_gemm(
    const unsigned* __restrict__ segs, const unsigned* __restrict__ recs,
    const unsigned short* __restrict__ hb,
    const unsigned short* __restrict__ Wt,     // [64][576] stacked bf16
    const float* __restrict__ bias, float* __restrict__ out) {
  __shared__ unsigned short Ss[64 * K2P];      // 74752 B
  const int tid = threadIdx.x;
  const int wave = tid >> 6, lane = tid & 63;
  const int r = lane >> 3, l8 = lane & 7;
  const int n0 = (int)blockIdx.x * 64;

  // ---- phase 1: aggregate 16 dsts per wave into LDS ----
  for (int j = 0; j < 16; ++j) {
    const int row = wave * 16 + j;
    const int d = n0 + row;
    bf16x8 ov = {};
    bf16x8 hv = {};
    if (d < NN) {
      const unsigned sg = segs[(size_t)d * NR + r];
      const int start = (int)(sg >> 8);
      const int len   = (int)(sg & 255u);
      const unsigned* po = recs + start;
      const unsigned short* hp = hb + l8 * 8;
      float a[8] = {};
      for (int jj = 0; jj < len; jj += 4) {
        unsigned rr[4];
#pragma unroll
        for (int sl = 0; sl < 4; ++sl)
          rr[sl] = (jj + sl < len) ? po[jj + sl] : 0u;
        bf16x8 vv[4];
#pragma unroll
        for (int sl = 0; sl < 4; ++sl) {
          const unsigned sv = (rr[sl] >> 9) & 0xFFFFu;   // < NN by construction
          vv[sl] = *(const bf16x8*)(hp + sv * 64);
        }
#pragma unroll
        for (int sl = 0; sl < 4; ++sl) {
          const float wk = (jj + sl < len) ? 1.f : 0.f;
#pragma unroll
          for (int q = 0; q < 8; ++q) a[q] += bf2f((unsigned short)vv[sl][q]) * wk;
        }
      }
      const float w = (len > 0) ? __builtin_amdgcn_rcpf((float)len) : 0.f;
#pragma unroll
      for (int q = 0; q < 8; ++q) ov[q] = (short)f2bf(a[q] * w);
      if (r == 0) hv = *(const bf16x8*)(hb + (size_t)d * 64 + l8 * 8);
    }
    *(bf16x8*)(Ss + row * K2P + r * 64 + l8 * 8) = ov;
    if (r == 0) *(bf16x8*)(Ss + row * K2P + 512 + l8 * 8) = hv;
  }
  __syncthreads();

  // ---- phase 2: out = Ss @ W2stack + b2 (swapped MFMA, verified R21) ----
  const int i16 = lane & 15, quad = lane >> 4;
  const int node = n0 + wave * 16 + i16;
  const unsigned short* As = Ss + (wave * 16 + i16) * K2P;

  f32x4 acc[4] = {};
#pragma unroll
  for (int kc = 0; kc < 18; ++kc) {
    const int k0 = kc * 32 + quad * 8;
    const bf16x8 a0 = *(const bf16x8*)(As + k0);
    const bf16x8 b0 = *(const bf16x8*)(Wt + (size_t)(i16)      * K2 + k0);
    const bf16x8 b1 = *(const bf16x8*)(Wt + (size_t)(i16 + 16) * K2 + k0);
    const bf16x8 b2 = *(const bf16x8*)(Wt + (size_t)(i16 + 32) * K2 + k0);
    const bf16x8 b3 = *(const bf16x8*)(Wt + (size_t)(i16 + 48) * K2 + k0);
    acc[0] = __builtin_amdgcn_mfma_f32_16x16x32_bf16(b0, a0, acc[0], 0, 0, 0);
    acc[1] = __builtin_amdgcn_mfma_f32_16x16x32_bf16(b1, a0, acc[1], 0, 0, 0);
    acc[2] = __builtin_amdgcn_mfma_f32_16x16x32_bf16(b2, a0, acc[2], 0, 0, 0);
    acc[3] = __builtin_amdgcn_mfma_f32_16x16x32_bf16(b3, a0, acc[3], 0, 0, 0);
  }

  if (node < NN) {
#pragma unroll
    for (int ct = 0; ct < 4; ++ct) {
      const float4 bv = *(const float4*)(bias + ct * 16 + quad * 4);
      float* p = out + (size_t)node * 64 + ct * 16 + quad * 4;
      *(float4*)p = make_float4(acc[ct][0] + bv.x, acc[ct][1] + bv.y,
                                acc[ct][2] + bv.z, acc[ct][3] + bv.w);
    }
  }
}

extern "C" void kernel_launch(void* const* d_in, const int* in_sizes, int n_in,
                              void* d_out, int out_size, void* d_ws, size_t ws_size,
                              hipStream_t stream) {
  const float* x   = (const float*)d_in[0];
  const int*   ei  = (const int*)d_in[1];
  const int*   et  = (const int*)d_in[2];
  const float* W1r = (const float*)d_in[3];
  const float* W1o = (const float*)d_in[4];
  const float* b1  = (const float*)d_in[5];
  const float* W2r = (const float*)d_in[6];
  const float* W2o = (const float*)d_in[7];
  const float* b2  = (const float*)d_in[8];
  float* out = (float*)d_out;

  const int* src = ei;
  const int* dst = ei + NE;

  char* ws = (char*)d_ws;
  size_t off = 0;
  auto alloc = [&](size_t bytes) {
    void* p = ws + off; off += (bytes + 255) & ~(size_t)255; return p;
  };
  int*   bcur      = (int*)alloc((size_t)NB * 4);
  int*   row_start = (int*)alloc((size_t)NN * 4);
  int*   deg       = (int*)alloc((size_t)NN * 4);
  unsigned* segs   = (unsigned*)alloc((size_t)NN * NR * 4);                 //  1.6 MB
  unsigned* brecs  = (unsigned*)alloc((size_t)NB * CAP * 4);                //  9.6 MB
  unsigned* recs   = (unsigned*)alloc((size_t)NB * CAP * 4);                //  9.6 MB
  unsigned short* xw    = (unsigned short*)alloc((size_t)NN * NR * 64 * 2); // 51.2 MB
  unsigned short* hb    = (unsigned short*)alloc((size_t)NN * FH * 2);      //  6.4 MB
  float*          hroot = (float*)alloc((size_t)NN * 64 * 4);               // 12.8 MB
  unsigned short* Wt1   = (unsigned short*)alloc((size_t)(NR + 1) * 64 * FIN * 2);
  unsigned short* Wt2b  = (unsigned short*)alloc((size_t)64 * K2 * 2);

  const int nprep = (NR + 1) * 64 * FIN + 64 * K2;
  prep<<<(nprep + 255) / 256, 256, 0, stream>>>(W1r, W1o, W2r, W2o, Wt1, Wt2b, bcur);

  const int gemm_blocks = (NN + 63) / 64;              // 782
  const int agg_blocks  = (NN * 64 + 255) / 256;       // 12500
  constexpr int SM1 = CH * 8 + 4 * NB * 4 + 16;        // 39040 (>= gemm 34816)

  // Layer 1 transform || CSR append (interleaved roles), then finalize.
  fused_append_gemm1<<<NAPP + gemm_blocks, 256, SM1, stream>>>(
      src, dst, et, bcur, brecs, x, Wt1, b1, xw, hroot);
  bucket_finalize<<<NB, 256, 0, stream>>>(bcur, brecs, row_start, deg, recs, segs);

  // Layer 1 aggregate, Layer 2 fused aggregate+transform.
  agg1<<<agg_blocks, 256, 0, stream>>>(row_start, deg, recs, xw, hroot, hb);
  agg2_gemm<<<gemm_blocks, 256, 0, stream>>>(segs, recs, hb, Wt2b, b2, out);
}